// Round 5
// baseline (748.451 us; speedup 1.0000x reference)
//
#include <hip/hip_runtime.h>
#include <stdint.h>

#define DIMN 1024
#define SEQN 2048
#define BATCHN 2
#define NCHUNK 8
#define CHUNKSZ 256
#define VOCABN 32000
#define ROWS_PB 6016            // sum of padded nk per batch
#define PSTRIDE_B (256*ROWS_PB) // P elements per batch
#define LN_EPS 1e-5f

#define MBIG 4096
#define NBIG 32000
#define KBIG 1024
#define NTILES_K (KBIG/64)      // 16

// column split for the vocab-GEMM A/B experiment
#define NSPLIT 16128            // cols [0,16128) -> 256^2 kernel (63 tiles)
                                // cols [16128,32000) -> 128^2 kernel (124 tiles)

typedef unsigned short ushort_t;
typedef __attribute__((ext_vector_type(8))) __bf16 bf16x8;
typedef __attribute__((ext_vector_type(4))) float f32x4;

__device__ const int d_nk[8]   = {256,512,768,769,769,769,769,770};
__device__ const int d_np[8]   = {256,512,768,896,896,896,896,896};
__device__ const int d_koff[8] = {0,256,768,1536,2432,3328,4224,5120};

__device__ __forceinline__ ushort_t f2bu(float f) {
  union { float f; unsigned u; } v; v.f = f;
  unsigned r = v.u + 0x7FFFu + ((v.u >> 16) & 1u);
  return (ushort_t)(r >> 16);
}
__device__ __forceinline__ float b2f(ushort_t u) {
  union { unsigned u; float f; } v; v.u = ((unsigned)u) << 16; return v.f;
}

// pos in [0,SEQ) of gathered key j for chunk i (closed form of _cache_positions)
__device__ __forceinline__ int pos_of(int i, int j) {
  if (i <= 2) return j;
  if (i <= 6) return (j == 0) ? 0 : (i - 3) * 256 + 255 + j;
  return (j == 0) ? 0 : ((j == 1) ? 1024 : 1278 + j);
}

__device__ __forceinline__ void gload16(const void* g, void* l) {
  __builtin_amdgcn_global_load_lds((__attribute__((address_space(1))) void*)g,
                                   (__attribute__((address_space(3))) void*)l,
                                   16, 0, 0);
}

// ---------------------------------------------------------------------------
// Core 128x128 tile bf16 MFMA loop (m97 structure): 256 threads, 4 waves,
// BK=64, single 32 KiB LDS buffer, __syncthreads pacing.  ~3 blocks/CU.
// ---------------------------------------------------------------------------
__device__ __forceinline__ void mma_core(const ushort_t* __restrict__ A,
                                         const ushort_t* __restrict__ Bt,
                                         int K, ushort_t* lA, ushort_t* lB,
                                         f32x4 acc[4][4], int tid) {
  const int lane = tid & 63;
  const int wr = (tid >> 7) & 1;
  const int wc = (tid >> 6) & 1;
  const int frow = lane & 15;
  const int kocc = (lane >> 4) * 8;
  for (int kt = 0; kt < K; kt += 64) {
#pragma unroll
    for (int t = 0; t < 4; ++t) {
      int cid = t * 256 + tid;
      int row = cid >> 3;
      int cc  = (cid & 7) * 8;
      gload16(A  + (size_t)row * K + kt + cc, (char*)lA + cid * 16);
      gload16(Bt + (size_t)row * K + kt + cc, (char*)lB + cid * 16);
    }
    __syncthreads();
#pragma unroll
    for (int kk = 0; kk < 2; ++kk) {
      bf16x8 af[4], bfr[4];
#pragma unroll
      for (int m = 0; m < 4; ++m)
        af[m] = *(const bf16x8*)(lA + (wr*64 + m*16 + frow)*64 + kk*32 + kocc);
#pragma unroll
      for (int n = 0; n < 4; ++n)
        bfr[n] = *(const bf16x8*)(lB + (wc*64 + n*16 + frow)*64 + kk*32 + kocc);
#pragma unroll
      for (int m = 0; m < 4; ++m)
#pragma unroll
        for (int n = 0; n < 4; ++n)
          acc[m][n] = __builtin_amdgcn_mfma_f32_16x16x32_bf16(af[m], bfr[n],
                                                              acc[m][n], 0, 0, 0);
    }
    __syncthreads();
  }
}

// ===========================================================================
// A/B kernel 1: vocab cols [NSPLIT, 32000) via m97 128^2 structure.
// Grid: 3968 blocks = 124 nt x 32 mt; XCD-chunked, m-fastest within chunk ->
// each XCD's ~32 concurrent blocks share one B panel (L2-resident) and
// stream A (8 MB, L3-resident).
// ===========================================================================
__global__ __launch_bounds__(256) void k_vocab128(
    const ushort_t* __restrict__ A, const ushort_t* __restrict__ Bt,
    const float* __restrict__ bias, float* __restrict__ C) {
  const int G = (int)gridDim.x;
  int l = blockIdx.x;
  int swz = (l & 7) * (G >> 3) + (l >> 3);
  const int mt = swz & 31;               // 32 m-tiles
  const int nt = swz >> 5;               // 0..123
  const int col0 = NSPLIT;
  __shared__ __align__(16) ushort_t lA[128*64];
  __shared__ __align__(16) ushort_t lB[128*64];
  f32x4 acc[4][4] = {};
  const int tid = threadIdx.x;
  mma_core(A + (size_t)mt * 128 * KBIG,
           Bt + ((size_t)col0 + (size_t)nt * 128) * KBIG,
           KBIG, lA, lB, acc, tid);
  const int lane = tid & 63, wr = (tid >> 7) & 1, wc = (tid >> 6) & 1;
  const int rbase = mt * 128 + wr * 64 + (lane >> 4) * 4;
  const int cbase = col0 + nt * 128 + wc * 64 + (lane & 15);
#pragma unroll
  for (int m = 0; m < 4; ++m)
#pragma unroll
    for (int n = 0; n < 4; ++n) {
      int c = cbase + n * 16;
      float bv = bias[c];
#pragma unroll
      for (int j = 0; j < 4; ++j)
        C[(size_t)(rbase + m * 16 + j) * NBIG + c] = acc[m][n][j] + bv;
    }
}

// ===========================================================================
// A/B kernel 2: vocab cols [0, NSPLIT) via the r1 256^2 8-wave schedule
// (best 256^2 measured: stage whole next tile, vmcnt(8) gate, quadrant
// barriers, setprio per quadrant).  1008 blocks = 63 nt x 16 mt.
// ===========================================================================
__device__ __forceinline__ void stage_tile_big(const char* Abase, const char* Bbase,
                                               ushort_t* ldsbuf, int ktile, int tid) {
  const size_t ldb = (size_t)KBIG * 2;
#pragma unroll
  for (int s = 0; s < 4; ++s) {
    const char* base = (s < 2 ? Abase : Bbase) + (size_t)(s & 1) * 128 * ldb
                       + (size_t)ktile * 128;   // 64 bf16 cols = 128 B
    ushort_t* lh = ldsbuf + s * 8192;
#pragma unroll
    for (int r2 = 0; r2 < 2; ++r2) {
      int c = r2 * 512 + tid;                  // 16B chunk id; wave-linear LDS
      int row = c >> 3;                        // 0..127
      int off_l = (c * 16) ^ ((row & 7) << 4); // inverse swizzle on source
      gload16(base + (size_t)row * ldb + (off_l & 127), (char*)lh + c * 16);
    }
  }
}

__global__ __launch_bounds__(512, 2) void k_vocab256(
    const ushort_t* __restrict__ A, const ushort_t* __restrict__ Bt,
    const float* __restrict__ bias, float* __restrict__ C) {
  __shared__ ushort_t lds[2][4][8192];   // per buf {A-h0, A-h1, B-h0, B-h1}
  const int tid = threadIdx.x;
  const int lane = tid & 63, w = tid >> 6, wm = w >> 2, wn = w & 3;
  const int frow = lane & 15, lhi = lane >> 4;
  const int xk = (frow & 7) << 4;        // read-side swizzle XOR

  int l = blockIdx.x;
  int swz = (l & 7) * ((int)gridDim.x >> 3) + (l >> 3);
  const int mt = swz & 15;               // 16 m-tiles
  const int nt = swz >> 4;               // 0..62
  const char* Abase = (const char*)(A + (size_t)mt * 256 * KBIG);
  const char* Bbase = (const char*)(Bt + (size_t)nt * 256 * KBIG);

  f32x4 acc[8][4] = {};

  stage_tile_big(Abase, Bbase, &lds[0][0][0], 0, tid);

  for (int kt = 0; kt < NTILES_K; ++kt) {
    const int cur = kt & 1;
    __builtin_amdgcn_sched_barrier(0);
    if (kt + 1 < NTILES_K) {
      stage_tile_big(Abase, Bbase, &lds[cur ^ 1][0][0], kt + 1, tid);
      asm volatile("s_waitcnt vmcnt(8)");    // oldest 8 = tile kt landed
    } else {
      asm volatile("s_waitcnt vmcnt(0)");
    }
    __builtin_amdgcn_s_barrier();
    __builtin_amdgcn_sched_barrier(0);

    const char* lA = (const char*)&lds[cur][wm][0];
    const char* lB = (const char*)&lds[cur][2 + (wn >> 1)][0];

    bf16x8 bF[4][2];
#pragma unroll
    for (int fc = 0; fc < 4; ++fc) {
      int c = (wn & 1) * 64 + fc * 16 + frow;
#pragma unroll
      for (int kk = 0; kk < 2; ++kk)
        bF[fc][kk] = *(const bf16x8*)(lB + ((c * 128 + kk * 64 + lhi * 16) ^ xk));
    }
#pragma unroll
    for (int q = 0; q < 4; ++q) {
      bf16x8 aF[2][2];
#pragma unroll
      for (int i = 0; i < 2; ++i) {
        int r = (2 * q + i) * 16 + frow;
#pragma unroll
        for (int kk = 0; kk < 2; ++kk)
          aF[i][kk] = *(const bf16x8*)(lA + ((r * 128 + kk * 64 + lhi * 16) ^ xk));
      }
      if (q) __builtin_amdgcn_s_barrier();
      __builtin_amdgcn_s_setprio(1);
#pragma unroll
      for (int i = 0; i < 2; ++i)
#pragma unroll
        for (int fc = 0; fc < 4; ++fc)
#pragma unroll
          for (int kk = 0; kk < 2; ++kk)
            acc[2 * q + i][fc] = __builtin_amdgcn_mfma_f32_16x16x32_bf16(
                aF[i][kk], bF[fc][kk], acc[2 * q + i][fc], 0, 0, 0);
      __builtin_amdgcn_s_setprio(0);
    }
    __builtin_amdgcn_s_barrier();
  }

  const int rbase = mt * 256 + wm * 128 + lhi * 4;
  const int cbase = nt * 256 + wn * 64 + frow;
#pragma unroll
  for (int fc = 0; fc < 4; ++fc) {
    float bv = bias[cbase + fc * 16];
#pragma unroll
    for (int fr = 0; fr < 8; ++fr)
#pragma unroll
      for (int j = 0; j < 4; ++j)
        C[(size_t)(rbase + fr * 16 + j) * NBIG + cbase + fc * 16] =
            acc[fr][fc][j] + bv;
  }
}

// ---------------------------------------------------------------------------
__global__ __launch_bounds__(256) void k_cvt(const float* __restrict__ src,
                                             ushort_t* __restrict__ dst, int n) {
  int idx = blockIdx.x * 256 + threadIdx.x;
  int stride = gridDim.x * 256;
  int n4 = n >> 2;
  for (int i = idx; i < n4; i += stride) {
    float4 v = ((const float4*)src)[i];
    ((ushort4*)dst)[i] = make_ushort4(f2bu(v.x), f2bu(v.y), f2bu(v.z), f2bu(v.w));
  }
}

// ctx[b,t] = sum_{o=0..3, t-o>=0} emb[x[b,t-o]]  -> bf16
__global__ __launch_bounds__(256) void k_embed(const int* __restrict__ x,
                                               const float* __restrict__ emb,
                                               ushort_t* __restrict__ ctxb) {
  const int t = blockIdx.x, b = blockIdx.y, tid = threadIdx.x;
  float4 s = make_float4(0.f, 0.f, 0.f, 0.f);
#pragma unroll
  for (int o = 0; o < 4; ++o) {
    if (t - o < 0) break;
    int tok = x[b * SEQN + t - o];
    float4 v = ((const float4*)(emb + (size_t)tok * DIMN))[tid];
    s.x += v.x; s.y += v.y; s.z += v.z; s.w += v.w;
  }
  ((ushort4*)(ctxb + ((size_t)(b * SEQN + t)) * DIMN))[tid] =
      make_ushort4(f2bu(s.x), f2bu(s.y), f2bu(s.z), f2bu(s.w));
}

__global__ __launch_bounds__(256) void k_gemm_bf16(const ushort_t* __restrict__ A,
    const ushort_t* __restrict__ Bt, const float* __restrict__ bias,
    ushort_t* __restrict__ C, int N, int K) {
  __shared__ __align__(16) ushort_t lA[128*64];
  __shared__ __align__(16) ushort_t lB[128*64];
  f32x4 acc[4][4] = {};
  const int tid = threadIdx.x;
  mma_core(A + (size_t)blockIdx.y * 128 * K, Bt + (size_t)blockIdx.x * 128 * K,
           K, lA, lB, acc, tid);
  const int lane = tid & 63, wr = (tid >> 7) & 1, wc = (tid >> 6) & 1;
  const int rbase = blockIdx.y * 128 + wr * 64 + (lane >> 4) * 4;
  const int cbase = blockIdx.x * 128 + wc * 64 + (lane & 15);
#pragma unroll
  for (int m = 0; m < 4; ++m)
#pragma unroll
    for (int n = 0; n < 4; ++n) {
      int c = cbase + n * 16;
      float bv = bias[c];
#pragma unroll
      for (int j = 0; j < 4; ++j)
        C[(size_t)(rbase + m * 16 + j) * N + c] = f2bu(acc[m][n][j] + bv);
    }
}

__global__ __launch_bounds__(256) void k_gemm_f32(const ushort_t* __restrict__ A,
    const ushort_t* __restrict__ Bt, const float* __restrict__ bias,
    float* __restrict__ C, int N, int K) {
  __shared__ __align__(16) ushort_t lA[128*64];
  __shared__ __align__(16) ushort_t lB[128*64];
  f32x4 acc[4][4] = {};
  const int tid = threadIdx.x;
  mma_core(A + (size_t)blockIdx.y * 128 * K, Bt + (size_t)blockIdx.x * 128 * K,
           K, lA, lB, acc, tid);
  const int lane = tid & 63, wr = (tid >> 7) & 1, wc = (tid >> 6) & 1;
  const int rbase = blockIdx.y * 128 + wr * 64 + (lane >> 4) * 4;
  const int cbase = blockIdx.x * 128 + wc * 64 + (lane & 15);
#pragma unroll
  for (int m = 0; m < 4; ++m)
#pragma unroll
    for (int n = 0; n < 4; ++n) {
      int c = cbase + n * 16;
      float bv = bias[c];
#pragma unroll
      for (int j = 0; j < 4; ++j)
        C[(size_t)(rbase + m * 16 + j) * N + c] = acc[m][n][j] + bv;
    }
}

// gather K rows into padded contiguous [b][ROWS_PB][DIM] (zeros in pad)
__global__ __launch_bounds__(256) void k_gatherK(const ushort_t* __restrict__ Kb,
                                                 ushort_t* __restrict__ Kg) {
  const int r = blockIdx.x, b = blockIdx.y, tid = threadIdx.x;
  int i = 7;
#pragma unroll
  for (int q = 0; q < 7; ++q) if (r < d_koff[q + 1]) { i = q; break; }
  const int j = r - d_koff[i];
  ushort4* dst = (ushort4*)(Kg + ((size_t)b * ROWS_PB + r) * DIMN);
  if (j < d_nk[i]) {
    int pos = pos_of(i, j);
    dst[tid] = ((const ushort4*)(Kb + ((size_t)b * SEQN + pos) * DIMN))[tid];
  } else {
    dst[tid] = make_ushort4(0, 0, 0, 0);
  }
}

// transpose-gather V -> VgT[b][chunk]: [DIM][np] (zeros in pad)
__global__ __launch_bounds__(256) void k_transV(const ushort_t* __restrict__ Vb,
                                                ushort_t* __restrict__ VgT) {
  __shared__ ushort_t tile[64][66];
  const int z = blockIdx.z, b = z >> 3, i = z & 7;
  const int np = d_np[i], nk = d_nk[i], ko = d_koff[i];
  const int jb = blockIdx.x * 64;
  if (jb >= np) return;
  const int db = blockIdx.y * 64;
  const int tid = threadIdx.x, tx = tid & 63, ty = tid >> 6;
#pragma unroll
  for (int rep = 0; rep < 16; ++rep) {
    int jl = rep * 4 + ty;
    int j = jb + jl;
    ushort_t v = 0;
    if (j < nk) v = Vb[((size_t)b * SEQN + pos_of(i, j)) * DIMN + db + tx];
    tile[jl][tx] = v;
  }
  __syncthreads();
  const size_t base = ((size_t)b * ROWS_PB + ko) * DIMN;
#pragma unroll
  for (int rep = 0; rep < 16; ++rep) {
    int dl = rep * 4 + ty;
    VgT[base + (size_t)(db + dl) * np + jb + tx] = tile[tx][dl];
  }
}

// scores: P = exp(scale * Q Kg^T) with causal/pad mask -> bf16
__global__ __launch_bounds__(256) void k_scores(const ushort_t* __restrict__ Qb,
    const ushort_t* __restrict__ Kg, ushort_t* __restrict__ P) {
  const int z = blockIdx.z, b = z >> 3, i = z & 7;
  const int np = d_np[i], nk = d_nk[i], ko = d_koff[i];
  if ((int)blockIdx.x * 128 >= np) return;
  __shared__ __align__(16) ushort_t lA[128*64];
  __shared__ __align__(16) ushort_t lB[128*64];
  f32x4 acc[4][4] = {};
  const int tid = threadIdx.x;
  const ushort_t* A  = Qb + ((size_t)(b * SEQN + i * CHUNKSZ) + blockIdx.y * 128) * DIMN;
  const ushort_t* Bt = Kg + ((size_t)b * ROWS_PB + ko + blockIdx.x * 128) * DIMN;
  mma_core(A, Bt, DIMN, lA, lB, acc, tid);
  const int lane = tid & 63, wr = (tid >> 7) & 1, wc = (tid >> 6) & 1;
  const int rb = blockIdx.y * 128 + wr * 64 + (lane >> 4) * 4;
  const int cb = blockIdx.x * 128 + wc * 64 + (lane & 15);
  ushort_t* Pc = P + (size_t)b * PSTRIDE_B + (size_t)ko * 256;
  const float scale = 0.03125f;  // 1/sqrt(1024)
  const int diag0 = nk - CHUNKSZ;
#pragma unroll
  for (int m = 0; m < 4; ++m)
#pragma unroll
    for (int n = 0; n < 4; ++n) {
      int c = cb + n * 16;
#pragma unroll
      for (int j = 0; j < 4; ++j) {
        int r = rb + m * 16 + j;
        float w = 0.0f;
        if (c < nk && (c - diag0) <= r) w = expf(acc[m][n][j] * scale);
        Pc[(size_t)r * np + c] = f2bu(w);
      }
    }
}

// deterministic row sums of P (bf16 values, f32 accumulate)
__global__ __launch_bounds__(256) void k_rowsum(const ushort_t* __restrict__ P,
                                                float* __restrict__ rowsum) {
  const int z = blockIdx.y, b = z >> 3, i = z & 7, r = blockIdx.x;
  const int np = d_np[i], ko = d_koff[i];
  const ushort_t* row = P + (size_t)b * PSTRIDE_B + (size_t)ko * 256 + (size_t)r * np;
  const int tid = threadIdx.x;
  float s = 0.f;
  for (int c = tid; c < np; c += 256) s += b2f(row[c]);
#pragma unroll
  for (int o = 1; o < 64; o <<= 1) s += __shfl_xor(s, o);
  __shared__ float ss[4];
  if ((tid & 63) == 0) ss[tid >> 6] = s;
  __syncthreads();
  if (tid == 0) rowsum[z * 256 + r] = ss[0] + ss[1] + ss[2] + ss[3];
}

// attended = (P @ Vg) / rowsum -> bf16
__global__ __launch_bounds__(256) void k_pv(const ushort_t* __restrict__ P,
    const ushort_t* __restrict__ VgT, const float* __restrict__ rowsum,
    ushort_t* __restrict__ attb) {
  const int z = blockIdx.z, b = z >> 3, i = z & 7;
  const int np = d_np[i], ko = d_koff[i];
  __shared__ __align__(16) ushort_t lA[128*64];
  __shared__ __align__(16) ushort_t lB[128*64];
  f32x4 acc[4][4] = {};
  const int tid = threadIdx.x;
  const ushort_t* A  = P + (size_t)b * PSTRIDE_B + (size_t)ko * 256 +
                       (size_t)blockIdx.y * 128 * np;
  const ushort_t* Bt = VgT + ((size_t)b * ROWS_PB + ko) * DIMN +
                       (size_t)blockIdx.x * 128 * np;
  mma_core(A, Bt, np, lA, lB, acc, tid);
  const int lane = tid & 63, wr = (tid >> 7) & 1, wc = (tid >> 6) & 1;
  const int rb = blockIdx.y * 128 + wr * 64 + (lane >> 4) * 4;
  const int cb = blockIdx.x * 128 + wc * 64 + (lane & 15);
  const float* rs = rowsum + z * 256;
  ushort_t* outp = attb + (size_t)(b * SEQN + i * CHUNKSZ) * DIMN;
#pragma unroll
  for (int m = 0; m < 4; ++m)
#pragma unroll
    for (int j = 0; j < 4; ++j) {
      int r = rb + m * 16 + j;
      float inv = 1.0f / rs[r];
#pragma unroll
      for (int n = 0; n < 4; ++n)
        outp[(size_t)r * DIMN + cb + n * 16] = f2bu(acc[m][n][j] * inv);
    }
}

__global__ __launch_bounds__(256) void k_ln(const float* __restrict__ h,
    const float* __restrict__ lnw, const float* __restrict__ lnb,
    ushort_t* __restrict__ hb) {
  const int row = blockIdx.x, tid = threadIdx.x;
  float4 v = ((const float4*)(h + (size_t)row * DIMN))[tid];
  float s  = v.x + v.y + v.z + v.w;
  float sq = v.x * v.x + v.y * v.y + v.z * v.z + v.w * v.w;
#pragma unroll
  for (int o = 1; o < 64; o <<= 1) { s += __shfl_xor(s, o); sq += __shfl_xor(sq, o); }
  __shared__ float ss[4], ssq[4];
  if ((tid & 63) == 0) { ss[tid >> 6] = s; ssq[tid >> 6] = sq; }
  __syncthreads();
  s  = ss[0] + ss[1] + ss[2] + ss[3];
  sq = ssq[0] + ssq[1] + ssq[2] + ssq[3];
  const float mu  = s * (1.0f / DIMN);
  const float var = sq * (1.0f / DIMN) - mu * mu;
  const float inv = rsqrtf(var + LN_EPS);
  float4 w4 = ((const float4*)lnw)[tid];
  float4 b4 = ((const float4*)lnb)[tid];
  ushort4 o4 = make_ushort4(f2bu((v.x - mu) * inv * w4.x + b4.x),
                            f2bu((v.y - mu) * inv * w4.y + b4.y),
                            f2bu((v.z - mu) * inv * w4.z + b4.z),
                            f2bu((v.w - mu) * inv * w4.w + b4.w));
  ((ushort4*)(hb + (size_t)row * DIMN))[tid] = o4;
}

// ---------------------------------------------------------------------------
extern "C" void kernel_launch(void* const* d_in, const int* in_sizes, int n_in,
                              void* d_out, int out_size, void* d_ws, size_t ws_size,
                              hipStream_t stream) {
  const int*   x    = (const int*)  d_in[0];
  const float* emb  = (const float*)d_in[1];
  const float* qw   = (const float*)d_in[2];
  const float* qb   = (const float*)d_in[3];
  const float* kw   = (const float*)d_in[4];
  const float* kb   = (const float*)d_in[5];
  const float* vw   = (const float*)d_in[6];
  const float* vb   = (const float*)d_in[7];
  const float* ow   = (const float*)d_in[8];
  const float* ob   = (const float*)d_in[9];
  const float* lnw  = (const float*)d_in[10];
  const float* lnb  = (const float*)d_in[11];
  const float* outw = (const float*)d_in[12];
  const float* outb = (const float*)d_in[13];
  float* out = (float*)d_out;
  (void)in_sizes; (void)n_in; (void)out_size; (void)ws_size;

  char* ws = (char*)d_ws;
  size_t off = 0;
  auto alloc = [&](size_t bytes) {
    size_t r = off; off += (bytes + 255) & ~(size_t)255; return r;
  };
  ushort_t* wqb   = (ushort_t*)(ws + alloc((size_t)DIMN * DIMN * 2));
  ushort_t* wkb   = (ushort_t*)(ws + alloc((size_t)DIMN * DIMN * 2));
  ushort_t* wvb   = (ushort_t*)(ws + alloc((size_t)DIMN * DIMN * 2));
  ushort_t* wob   = (ushort_t*)(ws + alloc((size_t)DIMN * DIMN * 2));
  ushort_t* woutb = (ushort_t*)(ws + alloc((size_t)VOCABN * DIMN * 2));
  ushort_t* ctxb  = (ushort_t*)(ws + alloc((size_t)BATCHN * SEQN * DIMN * 2));
  ushort_t* Qb    = (ushort_t*)(ws + alloc((size_t)BATCHN * SEQN * DIMN * 2));
  ushort_t* Kb    = (ushort_t*)(ws + alloc((size_t)BATCHN * SEQN * DIMN * 2));
  ushort_t* Vb    = (ushort_t*)(ws + alloc((size_t)BATCHN * SEQN * DIMN * 2));
  ushort_t* Kg    = (ushort_t*)(ws + alloc((size_t)BATCHN * ROWS_PB * DIMN * 2));
  ushort_t* VgT   = (ushort_t*)(ws + alloc((size_t)BATCHN * ROWS_PB * DIMN * 2));
  ushort_t* Pm    = (ushort_t*)(ws + alloc((size_t)BATCHN * PSTRIDE_B * 2));
  float*    rsum  = (float*)   (ws + alloc((size_t)BATCHN * NCHUNK * 256 * 4));
  ushort_t* attb  = (ushort_t*)(ws + alloc((size_t)BATCHN * SEQN * DIMN * 2));
  float*    hbuf  = (float*)   (ws + alloc((size_t)BATCHN * SEQN * DIMN * 4));
  ushort_t* hb    = (ushort_t*)(ws + alloc((size_t)BATCHN * SEQN * DIMN * 2));

  // weight conversions f32 -> bf16
  k_cvt<<<dim3(1024), dim3(256), 0, stream>>>(qw,   wqb,   DIMN * DIMN);
  k_cvt<<<dim3(1024), dim3(256), 0, stream>>>(kw,   wkb,   DIMN * DIMN);
  k_cvt<<<dim3(1024), dim3(256), 0, stream>>>(vw,   wvb,   DIMN * DIMN);
  k_cvt<<<dim3(1024), dim3(256), 0, stream>>>(ow,   wob,   DIMN * DIMN);
  k_cvt<<<dim3(2048), dim3(256), 0, stream>>>(outw, woutb, VOCABN * DIMN);

  // embedding + 4-tap context sum
  k_embed<<<dim3(SEQN, BATCHN), dim3(256), 0, stream>>>(x, emb, ctxb);

  // QKV projections
  k_gemm_bf16<<<dim3(8, 32), dim3(256), 0, stream>>>(ctxb, wqb, qb, Qb, DIMN, DIMN);
  k_gemm_bf16<<<dim3(8, 32), dim3(256), 0, stream>>>(ctxb, wkb, kb, Kb, DIMN, DIMN);
  k_gemm_bf16<<<dim3(8, 32), dim3(256), 0, stream>>>(ctxb, wvb, vb, Vb, DIMN, DIMN);

  // sparse KV gather
  k_gatherK<<<dim3(ROWS_PB, BATCHN), dim3(256), 0, stream>>>(Kb, Kg);
  k_transV<<<dim3(14, 16, BATCHN * NCHUNK), dim3(256), 0, stream>>>(Vb, VgT);

  // attention
  k_scores<<<dim3(7, 2, BATCHN * NCHUNK), dim3(256), 0, stream>>>(Qb, Kg, Pm);
  k_rowsum<<<dim3(256, BATCHN * NCHUNK), dim3(256), 0, stream>>>(Pm, rsum);
  k_pv<<<dim3(8, 2, BATCHN * NCHUNK), dim3(256), 0, stream>>>(Pm, VgT, rsum, attb);

  // output projection + layernorm
  k_gemm_f32<<<dim3(8, 32), dim3(256), 0, stream>>>(attb, wob, ob, hbuf, DIMN, DIMN);
  k_ln<<<dim3(BATCHN * SEQN), dim3(256), 0, stream>>>(hbuf, lnw, lnb, hb);

  // vocab projection A/B: cols [0,16128) via 256^2, cols [16128,32000) via 128^2
  k_vocab256<<<dim3(1008), dim3(512), 0, stream>>>(hb, woutb, outb, out);
  k_vocab128<<<dim3(3968), dim3(256), 0, stream>>>(hb, woutb, outb, out);
}

// Round 6
// 685.890 us; speedup vs baseline: 1.0912x; 1.0912x over previous
//
#include <hip/hip_runtime.h>
#include <stdint.h>

#define DIMN 1024
#define SEQN 2048
#define BATCHN 2
#define NCHUNK 8
#define CHUNKSZ 256
#define VOCABN 32000
#define ROWS_PB 6016            // sum of padded nk per batch
#define PSTRIDE_B (256*ROWS_PB) // P elements per batch
#define LN_EPS 1e-5f

#define MBIG 4096
#define NBIG 32000
#define KBIG 1024
#define NKT 32                  // K-tiles of BK=32

typedef unsigned short ushort_t;
typedef __attribute__((ext_vector_type(8))) __bf16 bf16x8;
typedef __attribute__((ext_vector_type(4))) float f32x4;

__device__ const int d_nk[8]   = {256,512,768,769,769,769,769,770};
__device__ const int d_np[8]   = {256,512,768,896,896,896,896,896};
__device__ const int d_koff[8] = {0,256,768,1536,2432,3328,4224,5120};

__device__ __forceinline__ ushort_t f2bu(float f) {
  union { float f; unsigned u; } v; v.f = f;
  unsigned r = v.u + 0x7FFFu + ((v.u >> 16) & 1u);
  return (ushort_t)(r >> 16);
}
__device__ __forceinline__ float b2f(ushort_t u) {
  union { unsigned u; float f; } v; v.u = ((unsigned)u) << 16; return v.f;
}

// pos in [0,SEQ) of gathered key j for chunk i (closed form of _cache_positions)
__device__ __forceinline__ int pos_of(int i, int j) {
  if (i <= 2) return j;
  if (i <= 6) return (j == 0) ? 0 : (i - 3) * 256 + 255 + j;
  return (j == 0) ? 0 : ((j == 1) ? 1024 : 1278 + j);
}

__device__ __forceinline__ void gload16(const void* g, void* l) {
  __builtin_amdgcn_global_load_lds((__attribute__((address_space(1))) void*)g,
                                   (__attribute__((address_space(3))) void*)l,
                                   16, 0, 0);
}

// ===========================================================================
// Vocab projection: 256x256 8-wave, BK=32, 4-deep ring buffer (T3+T4 with
// REAL prefetch depth).  A: [4096][1024] bf16, Bt: [32000][1024] bf16,
// C = A*Bt^T + bias (fp32).
//   - ring of 4 K-tile buffers (32 KiB each: A 16K + B 16K); stage tile t+3
//     at tile t's gate -> loads have ~6 phases (>5k cyc) to land.
//   - counted s_waitcnt vmcnt(12) (= 3 tiles x 4 loads in flight); tail 8/4/0.
//   - swizzled LDS: element (row r, k-chunk lhi) at slot lhi^(r&3)^((r>>2)&3)
//     (2-way max on ds_read_b128 = free); staging uses linear LDS dest +
//     inverse-swizzled global source (global_load_lds rule).
//   - per tile: 2 phases x {ds_read 4-8 | lgkmcnt(0) fence | setprio+16 MFMA |
//     barrier}; 3 barriers/tile.
// ===========================================================================
__global__ __launch_bounds__(512, 2) void k_vocab(
    const ushort_t* __restrict__ A, const ushort_t* __restrict__ Bt,
    const float* __restrict__ bias, float* __restrict__ C) {
  __shared__ ushort_t lds[4][16384];    // 4 ring bufs x 32 KiB = 128 KiB
  const int tid = threadIdx.x;
  const int lane = tid & 63, w = tid >> 6, wm = w >> 2, wn = w & 3;
  const int frow = lane & 15, lhi = lane >> 4;
  const int S = lhi ^ (frow & 3) ^ (frow >> 2);   // per-lane swizzled k-slot

  // XCD swizzle (2000 % 8 == 0), m-fastest: per-XCD blocks share B panels.
  int l = blockIdx.x;
  int swz = (l & 7) * ((int)gridDim.x >> 3) + (l >> 3);
  const int mt = swz & 15;               // 16 m-tiles
  const int nt = swz >> 4;               // 125 n-tiles

  // staging: 4 chunks (16B) per thread per tile; linear LDS dest, inverse-
  // swizzled global source.
  const char* srcs[4];
  int coff[4];
  {
    const char* Ab = (const char*)(A + (size_t)mt * 256 * KBIG);
    const char* Bb = (const char*)(Bt + (size_t)nt * 256 * KBIG);
#pragma unroll
    for (int j = 0; j < 4; ++j) {
      int c = j * 512 + tid;                 // 0..2047 (A: 0..1023, B: rest)
      int cc = c & 1023;
      int r = cc >> 2;                       // tile row 0..255
      int s = cc & 3;                        // physical slot
      int lh = s ^ (r & 3) ^ ((r >> 2) & 3); // logical k-chunk stored here
      srcs[j] = (c < 1024 ? Ab : Bb) + (size_t)r * (KBIG * 2) + lh * 16;
      coff[j] = c * 16;
    }
  }
  const int aBase = (wm * 128 + frow) * 64 + S * 16;          // + f*1024
  const int bBase = 16384 + (wn * 64 + frow) * 64 + S * 16;   // + fc*1024

  f32x4 acc[8][4] = {};

#define STAGE_V(t_)                                                      \
  { char* d_ = (char*)&lds[(t_) & 3][0];                                 \
    _Pragma("unroll")                                                    \
    for (int j_ = 0; j_ < 4; ++j_)                                       \
      gload16(srcs[j_] + (size_t)(t_) * 64, d_ + coff[j_]); }

#define TILE_V(t_, DOSTAGE, VMCNT_ASM)                                   \
  { const char* bufp = (const char*)&lds[(t_) & 3][0];                   \
    if (DOSTAGE) STAGE_V((t_) + 3);                                      \
    asm volatile(VMCNT_ASM);                                             \
    __builtin_amdgcn_s_barrier();          /* tile t fully in LDS */     \
    __builtin_amdgcn_sched_barrier(0);                                   \
    bf16x8 bF[4], aF[4];                                                 \
    _Pragma("unroll")                                                    \
    for (int fc = 0; fc < 4; ++fc)                                       \
      bF[fc] = *(const bf16x8*)(bufp + bBase + fc * 1024);               \
    _Pragma("unroll")                                                    \
    for (int i = 0; i < 4; ++i)                                          \
      aF[i] = *(const bf16x8*)(bufp + aBase + i * 1024);                 \
    asm volatile("s_waitcnt lgkmcnt(0)");                                \
    __builtin_amdgcn_sched_barrier(0);                                   \
    __builtin_amdgcn_s_setprio(1);                                       \
    _Pragma("unroll")                                                    \
    for (int i = 0; i < 4; ++i)                                          \
      _Pragma("unroll")                                                  \
      for (int fc = 0; fc < 4; ++fc)                                     \
        acc[i][fc] = __builtin_amdgcn_mfma_f32_16x16x32_bf16(            \
            aF[i], bF[fc], acc[i][fc], 0, 0, 0);                         \
    __builtin_amdgcn_s_setprio(0);                                       \
    __builtin_amdgcn_s_barrier();          /* phase lockstep */          \
    _Pragma("unroll")                                                    \
    for (int i = 0; i < 4; ++i)                                          \
      aF[i] = *(const bf16x8*)(bufp + aBase + (4 + i) * 1024);           \
    asm volatile("s_waitcnt lgkmcnt(0)");                                \
    __builtin_amdgcn_sched_barrier(0);                                   \
    __builtin_amdgcn_s_setprio(1);                                       \
    _Pragma("unroll")                                                    \
    for (int i = 0; i < 4; ++i)                                          \
      _Pragma("unroll")                                                  \
      for (int fc = 0; fc < 4; ++fc)                                     \
        acc[4 + i][fc] = __builtin_amdgcn_mfma_f32_16x16x32_bf16(        \
            aF[i], bF[fc], acc[4 + i][fc], 0, 0, 0);                     \
    __builtin_amdgcn_s_setprio(0);                                       \
    __builtin_amdgcn_s_barrier();          /* frees buf for next stage */\
  }

  STAGE_V(0); STAGE_V(1); STAGE_V(2);      // prologue: 3 tiles in flight

  for (int t = 0; t < NKT - 3; ++t)        // t = 0..28, stages t+3 = 3..31
    TILE_V(t, true, "s_waitcnt vmcnt(12)");
  TILE_V(NKT - 3, false, "s_waitcnt vmcnt(8)");
  TILE_V(NKT - 2, false, "s_waitcnt vmcnt(4)");
  TILE_V(NKT - 1, false, "s_waitcnt vmcnt(0)");
#undef TILE_V
#undef STAGE_V

  const int rbase = mt * 256 + wm * 128 + lhi * 4;
  const int cbase = nt * 256 + wn * 64 + frow;
#pragma unroll
  for (int fc = 0; fc < 4; ++fc) {
    float bv = bias[cbase + fc * 16];
#pragma unroll
    for (int fr = 0; fr < 8; ++fr)
#pragma unroll
      for (int j = 0; j < 4; ++j)
        C[(size_t)(rbase + fr * 16 + j) * NBIG + cbase + fc * 16] =
            acc[fr][fc][j] + bv;
  }
}

// ---------------------------------------------------------------------------
// Core 128x128 tile bf16 MFMA loop (m97 structure) for the small GEMMs.
// ---------------------------------------------------------------------------
__device__ __forceinline__ void mma_core(const ushort_t* __restrict__ A,
                                         const ushort_t* __restrict__ Bt,
                                         int K, ushort_t* lA, ushort_t* lB,
                                         f32x4 acc[4][4], int tid) {
  const int lane = tid & 63;
  const int wr = (tid >> 7) & 1;
  const int wc = (tid >> 6) & 1;
  const int frow = lane & 15;
  const int kocc = (lane >> 4) * 8;
  for (int kt = 0; kt < K; kt += 64) {
#pragma unroll
    for (int t = 0; t < 4; ++t) {
      int cid = t * 256 + tid;
      int row = cid >> 3;
      int cc  = (cid & 7) * 8;
      gload16(A  + (size_t)row * K + kt + cc, (char*)lA + cid * 16);
      gload16(Bt + (size_t)row * K + kt + cc, (char*)lB + cid * 16);
    }
    __syncthreads();
#pragma unroll
    for (int kk = 0; kk < 2; ++kk) {
      bf16x8 af[4], bfr[4];
#pragma unroll
      for (int m = 0; m < 4; ++m)
        af[m] = *(const bf16x8*)(lA + (wr*64 + m*16 + frow)*64 + kk*32 + kocc);
#pragma unroll
      for (int n = 0; n < 4; ++n)
        bfr[n] = *(const bf16x8*)(lB + (wc*64 + n*16 + frow)*64 + kk*32 + kocc);
#pragma unroll
      for (int m = 0; m < 4; ++m)
#pragma unroll
        for (int n = 0; n < 4; ++n)
          acc[m][n] = __builtin_amdgcn_mfma_f32_16x16x32_bf16(af[m], bfr[n],
                                                              acc[m][n], 0, 0, 0);
    }
    __syncthreads();
  }
}

// ---------------------------------------------------------------------------
__global__ __launch_bounds__(256) void k_cvt(const float* __restrict__ src,
                                             ushort_t* __restrict__ dst, int n) {
  int idx = blockIdx.x * 256 + threadIdx.x;
  int stride = gridDim.x * 256;
  int n4 = n >> 2;
  for (int i = idx; i < n4; i += stride) {
    float4 v = ((const float4*)src)[i];
    ((ushort4*)dst)[i] = make_ushort4(f2bu(v.x), f2bu(v.y), f2bu(v.z), f2bu(v.w));
  }
}

// ctx[b,t] = sum_{o=0..3, t-o>=0} emb[x[b,t-o]]  -> bf16
__global__ __launch_bounds__(256) void k_embed(const int* __restrict__ x,
                                               const float* __restrict__ emb,
                                               ushort_t* __restrict__ ctxb) {
  const int t = blockIdx.x, b = blockIdx.y, tid = threadIdx.x;
  float4 s = make_float4(0.f, 0.f, 0.f, 0.f);
#pragma unroll
  for (int o = 0; o < 4; ++o) {
    if (t - o < 0) break;
    int tok = x[b * SEQN + t - o];
    float4 v = ((const float4*)(emb + (size_t)tok * DIMN))[tid];
    s.x += v.x; s.y += v.y; s.z += v.z; s.w += v.w;
  }
  ((ushort4*)(ctxb + ((size_t)(b * SEQN + t)) * DIMN))[tid] =
      make_ushort4(f2bu(s.x), f2bu(s.y), f2bu(s.z), f2bu(s.w));
}

__global__ __launch_bounds__(256) void k_gemm_bf16(const ushort_t* __restrict__ A,
    const ushort_t* __restrict__ Bt, const float* __restrict__ bias,
    ushort_t* __restrict__ C, int N, int K) {
  __shared__ __align__(16) ushort_t lA[128*64];
  __shared__ __align__(16) ushort_t lB[128*64];
  f32x4 acc[4][4] = {};
  const int tid = threadIdx.x;
  mma_core(A + (size_t)blockIdx.y * 128 * K, Bt + (size_t)blockIdx.x * 128 * K,
           K, lA, lB, acc, tid);
  const int lane = tid & 63, wr = (tid >> 7) & 1, wc = (tid >> 6) & 1;
  const int rbase = blockIdx.y * 128 + wr * 64 + (lane >> 4) * 4;
  const int cbase = blockIdx.x * 128 + wc * 64 + (lane & 15);
#pragma unroll
  for (int m = 0; m < 4; ++m)
#pragma unroll
    for (int n = 0; n < 4; ++n) {
      int c = cbase + n * 16;
      float bv = bias[c];
#pragma unroll
      for (int j = 0; j < 4; ++j)
        C[(size_t)(rbase + m * 16 + j) * N + c] = f2bu(acc[m][n][j] + bv);
    }
}

__global__ __launch_bounds__(256) void k_gemm_f32(const ushort_t* __restrict__ A,
    const ushort_t* __restrict__ Bt, const float* __restrict__ bias,
    float* __restrict__ C, int N, int K) {
  __shared__ __align__(16) ushort_t lA[128*64];
  __shared__ __align__(16) ushort_t lB[128*64];
  f32x4 acc[4][4] = {};
  const int tid = threadIdx.x;
  mma_core(A + (size_t)blockIdx.y * 128 * K, Bt + (size_t)blockIdx.x * 128 * K,
           K, lA, lB, acc, tid);
  const int lane = tid & 63, wr = (tid >> 7) & 1, wc = (tid >> 6) & 1;
  const int rbase = blockIdx.y * 128 + wr * 64 + (lane >> 4) * 4;
  const int cbase = blockIdx.x * 128 + wc * 64 + (lane & 15);
#pragma unroll
  for (int m = 0; m < 4; ++m)
#pragma unroll
    for (int n = 0; n < 4; ++n) {
      int c = cbase + n * 16;
      float bv = bias[c];
#pragma unroll
      for (int j = 0; j < 4; ++j)
        C[(size_t)(rbase + m * 16 + j) * N + c] = acc[m][n][j] + bv;
    }
}

// gather K rows into padded contiguous [b][ROWS_PB][DIM] (zeros in pad)
__global__ __launch_bounds__(256) void k_gatherK(const ushort_t* __restrict__ Kb,
                                                 ushort_t* __restrict__ Kg) {
  const int r = blockIdx.x, b = blockIdx.y, tid = threadIdx.x;
  int i = 7;
#pragma unroll
  for (int q = 0; q < 7; ++q) if (r < d_koff[q + 1]) { i = q; break; }
  const int j = r - d_koff[i];
  ushort4* dst = (ushort4*)(Kg + ((size_t)b * ROWS_PB + r) * DIMN);
  if (j < d_nk[i]) {
    int pos = pos_of(i, j);
    dst[tid] = ((const ushort4*)(Kb + ((size_t)b * SEQN + pos) * DIMN))[tid];
  } else {
    dst[tid] = make_ushort4(0, 0, 0, 0);
  }
}

// transpose-gather V -> VgT[b][chunk]: [DIM][np] (zeros in pad)
__global__ __launch_bounds__(256) void k_transV(const ushort_t* __restrict__ Vb,
                                                ushort_t* __restrict__ VgT) {
  __shared__ ushort_t tile[64][66];
  const int z = blockIdx.z, b = z >> 3, i = z & 7;
  const int np = d_np[i], nk = d_nk[i], ko = d_koff[i];
  const int jb = blockIdx.x * 64;
  if (jb >= np) return;
  const int db = blockIdx.y * 64;
  const int tid = threadIdx.x, tx = tid & 63, ty = tid >> 6;
#pragma unroll
  for (int rep = 0; rep < 16; ++rep) {
    int jl = rep * 4 + ty;
    int j = jb + jl;
    ushort_t v = 0;
    if (j < nk) v = Vb[((size_t)b * SEQN + pos_of(i, j)) * DIMN + db + tx];
    tile[jl][tx] = v;
  }
  __syncthreads();
  const size_t base = ((size_t)b * ROWS_PB + ko) * DIMN;
#pragma unroll
  for (int rep = 0; rep < 16; ++rep) {
    int dl = rep * 4 + ty;
    VgT[base + (size_t)(db + dl) * np + jb + tx] = tile[tx][dl];
  }
}

// scores: P = exp(scale * Q Kg^T) with causal/pad mask -> bf16
__global__ __launch_bounds__(256) void k_scores(const ushort_t* __restrict__ Qb,
    const ushort_t* __restrict__ Kg, ushort_t* __restrict__ P) {
  const int z = blockIdx.z, b = z >> 3, i = z & 7;
  const int np = d_np[i], nk = d_nk[i], ko = d_koff[i];
  if ((int)blockIdx.x * 128 >= np) return;
  __shared__ __align__(16) ushort_t lA[128*64];
  __shared__ __align__(16) ushort_t lB[128*64];
  f32x4 acc[4][4] = {};
  const int tid = threadIdx.x;
  const ushort_t* A  = Qb + ((size_t)(b * SEQN + i * CHUNKSZ) + blockIdx.y * 128) * DIMN;
  const ushort_t* Bt = Kg + ((size_t)b * ROWS_PB + ko + blockIdx.x * 128) * DIMN;
  mma_core(A, Bt, DIMN, lA, lB, acc, tid);
  const int lane = tid & 63, wr = (tid >> 7) & 1, wc = (tid >> 6) & 1;
  const int rb = blockIdx.y * 128 + wr * 64 + (lane >> 4) * 4;
  const int cb = blockIdx.x * 128 + wc * 64 + (lane & 15);
  ushort_t* Pc = P + (size_t)b * PSTRIDE_B + (size_t)ko * 256;
  const float scale = 0.03125f;  // 1/sqrt(1024)
  const int diag0 = nk - CHUNKSZ;
#pragma unroll
  for (int m = 0; m < 4; ++m)
#pragma unroll
    for (int n = 0; n < 4; ++n) {
      int c = cb + n * 16;
#pragma unroll
      for (int j = 0; j < 4; ++j) {
        int r = rb + m * 16 + j;
        float w = 0.0f;
        if (c < nk && (c - diag0) <= r) w = expf(acc[m][n][j] * scale);
        Pc[(size_t)r * np + c] = f2bu(w);
      }
    }
}

// deterministic row sums of P (bf16 values, f32 accumulate)
__global__ __launch_bounds__(256) void k_rowsum(const ushort_t* __restrict__ P,
                                                float* __restrict__ rowsum) {
  const int z = blockIdx.y, b = z >> 3, i = z & 7, r = blockIdx.x;
  const int np = d_np[i], ko = d_koff[i];
  const ushort_t* row = P + (size_t)b * PSTRIDE_B + (size_t)ko * 256 + (size_t)r * np;
  const int tid = threadIdx.x;
  float s = 0.f;
  for (int c = tid; c < np; c += 256) s += b2f(row[c]);
#pragma unroll
  for (int o = 1; o < 64; o <<= 1) s += __shfl_xor(s, o);
  __shared__ float ss[4];
  if ((tid & 63) == 0) ss[tid >> 6] = s;
  __syncthreads();
  if (tid == 0) rowsum[z * 256 + r] = ss[0] + ss[1] + ss[2] + ss[3];
}

// attended = (P @ Vg) / rowsum -> bf16
__global__ __launch_bounds__(256) void k_pv(const ushort_t* __restrict__ P,
    const ushort_t* __restrict__ VgT, const float* __restrict__ rowsum,
    ushort_t* __restrict__ attb) {
  const int z = blockIdx.z, b = z >> 3, i = z & 7;
  const int np = d_np[i], ko = d_koff[i];
  __shared__ __align__(16) ushort_t lA[128*64];
  __shared__ __align__(16) ushort_t lB[128*64];
  f32x4 acc[4][4] = {};
  const int tid = threadIdx.x;
  const ushort_t* A  = P + (size_t)b * PSTRIDE_B + (size_t)ko * 256 +
                       (size_t)blockIdx.y * 128 * np;
  const ushort_t* Bt = VgT + ((size_t)b * ROWS_PB + ko) * DIMN +
                       (size_t)blockIdx.x * 128 * np;
  mma_core(A, Bt, np, lA, lB, acc, tid);
  const int lane = tid & 63, wr = (tid >> 7) & 1, wc = (tid >> 6) & 1;
  const int rb = blockIdx.y * 128 + wr * 64 + (lane >> 4) * 4;
  const int cb = blockIdx.x * 128 + wc * 64 + (lane & 15);
  const float* rs = rowsum + z * 256;
  ushort_t* outp = attb + (size_t)(b * SEQN + i * CHUNKSZ) * DIMN;
#pragma unroll
  for (int m = 0; m < 4; ++m)
#pragma unroll
    for (int j = 0; j < 4; ++j) {
      int r = rb + m * 16 + j;
      float inv = 1.0f / rs[r];
#pragma unroll
      for (int n = 0; n < 4; ++n)
        outp[(size_t)r * DIMN + cb + n * 16] = f2bu(acc[m][n][j] * inv);
    }
}

__global__ __launch_bounds__(256) void k_ln(const float* __restrict__ h,
    const float* __restrict__ lnw, const float* __restrict__ lnb,
    ushort_t* __restrict__ hb) {
  const int row = blockIdx.x, tid = threadIdx.x;
  float4 v = ((const float4*)(h + (size_t)row * DIMN))[tid];
  float s  = v.x + v.y + v.z + v.w;
  float sq = v.x * v.x + v.y * v.y + v.z * v.z + v.w * v.w;
#pragma unroll
  for (int o = 1; o < 64; o <<= 1) { s += __shfl_xor(s, o); sq += __shfl_xor(sq, o); }
  __shared__ float ss[4], ssq[4];
  if ((tid & 63) == 0) { ss[tid >> 6] = s; ssq[tid >> 6] = sq; }
  __syncthreads();
  s  = ss[0] + ss[1] + ss[2] + ss[3];
  sq = ssq[0] + ssq[1] + ssq[2] + ssq[3];
  const float mu  = s * (1.0f / DIMN);
  const float var = sq * (1.0f / DIMN) - mu * mu;
  const float inv = rsqrtf(var + LN_EPS);
  float4 w4 = ((const float4*)lnw)[tid];
  float4 b4 = ((const float4*)lnb)[tid];
  ushort4 o4 = make_ushort4(f2bu((v.x - mu) * inv * w4.x + b4.x),
                            f2bu((v.y - mu) * inv * w4.y + b4.y),
                            f2bu((v.z - mu) * inv * w4.z + b4.z),
                            f2bu((v.w - mu) * inv * w4.w + b4.w));
  ((ushort4*)(hb + (size_t)row * DIMN))[tid] = o4;
}

// ---------------------------------------------------------------------------
extern "C" void kernel_launch(void* const* d_in, const int* in_sizes, int n_in,
                              void* d_out, int out_size, void* d_ws, size_t ws_size,
                              hipStream_t stream) {
  const int*   x    = (const int*)  d_in[0];
  const float* emb  = (const float*)d_in[1];
  const float* qw   = (const float*)d_in[2];
  const float* qb   = (const float*)d_in[3];
  const float* kw   = (const float*)d_in[4];
  const float* kb   = (const float*)d_in[5];
  const float* vw   = (const float*)d_in[6];
  const float* vb   = (const float*)d_in[7];
  const float* ow   = (const float*)d_in[8];
  const float* ob   = (const float*)d_in[9];
  const float* lnw  = (const float*)d_in[10];
  const float* lnb  = (const float*)d_in[11];
  const float* outw = (const float*)d_in[12];
  const float* outb = (const float*)d_in[13];
  float* out = (float*)d_out;
  (void)in_sizes; (void)n_in; (void)out_size; (void)ws_size;

  char* ws = (char*)d_ws;
  size_t off = 0;
  auto alloc = [&](size_t bytes) {
    size_t r = off; off += (bytes + 255) & ~(size_t)255; return r;
  };
  ushort_t* wqb   = (ushort_t*)(ws + alloc((size_t)DIMN * DIMN * 2));
  ushort_t* wkb   = (ushort_t*)(ws + alloc((size_t)DIMN * DIMN * 2));
  ushort_t* wvb   = (ushort_t*)(ws + alloc((size_t)DIMN * DIMN * 2));
  ushort_t* wob   = (ushort_t*)(ws + alloc((size_t)DIMN * DIMN * 2));
  ushort_t* woutb = (ushort_t*)(ws + alloc((size_t)VOCABN * DIMN * 2));
  ushort_t* ctxb  = (ushort_t*)(ws + alloc((size_t)BATCHN * SEQN * DIMN * 2));
  ushort_t* Qb    = (ushort_t*)(ws + alloc((size_t)BATCHN * SEQN * DIMN * 2));
  ushort_t* Kb    = (ushort_t*)(ws + alloc((size_t)BATCHN * SEQN * DIMN * 2));
  ushort_t* Vb    = (ushort_t*)(ws + alloc((size_t)BATCHN * SEQN * DIMN * 2));
  ushort_t* Kg    = (ushort_t*)(ws + alloc((size_t)BATCHN * ROWS_PB * DIMN * 2));
  ushort_t* VgT   = (ushort_t*)(ws + alloc((size_t)BATCHN * ROWS_PB * DIMN * 2));
  ushort_t* Pm    = (ushort_t*)(ws + alloc((size_t)BATCHN * PSTRIDE_B * 2));
  float*    rsum  = (float*)   (ws + alloc((size_t)BATCHN * NCHUNK * 256 * 4));
  ushort_t* attb  = (ushort_t*)(ws + alloc((size_t)BATCHN * SEQN * DIMN * 2));
  float*    hbuf  = (float*)   (ws + alloc((size_t)BATCHN * SEQN * DIMN * 4));
  ushort_t* hb    = (ushort_t*)(ws + alloc((size_t)BATCHN * SEQN * DIMN * 2));

  // weight conversions f32 -> bf16
  k_cvt<<<dim3(1024), dim3(256), 0, stream>>>(qw,   wqb,   DIMN * DIMN);
  k_cvt<<<dim3(1024), dim3(256), 0, stream>>>(kw,   wkb,   DIMN * DIMN);
  k_cvt<<<dim3(1024), dim3(256), 0, stream>>>(vw,   wvb,   DIMN * DIMN);
  k_cvt<<<dim3(1024), dim3(256), 0, stream>>>(ow,   wob,   DIMN * DIMN);
  k_cvt<<<dim3(2048), dim3(256), 0, stream>>>(outw, woutb, VOCABN * DIMN);

  // embedding + 4-tap context sum
  k_embed<<<dim3(SEQN, BATCHN), dim3(256), 0, stream>>>(x, emb, ctxb);

  // QKV projections
  k_gemm_bf16<<<dim3(8, 32), dim3(256), 0, stream>>>(ctxb, wqb, qb, Qb, DIMN, DIMN);
  k_gemm_bf16<<<dim3(8, 32), dim3(256), 0, stream>>>(ctxb, wkb, kb, Kb, DIMN, DIMN);
  k_gemm_bf16<<<dim3(8, 32), dim3(256), 0, stream>>>(ctxb, wvb, vb, Vb, DIMN, DIMN);

  // sparse KV gather
  k_gatherK<<<dim3(ROWS_PB, BATCHN), dim3(256), 0, stream>>>(Kb, Kg);
  k_transV<<<dim3(14, 16, BATCHN * NCHUNK), dim3(256), 0, stream>>>(Vb, VgT);

  // attention
  k_scores<<<dim3(7, 2, BATCHN * NCHUNK), dim3(256), 0, stream>>>(Qb, Kg, Pm);
  k_rowsum<<<dim3(256, BATCHN * NCHUNK), dim3(256), 0, stream>>>(Pm, rsum);
  k_pv<<<dim3(8, 2, BATCHN * NCHUNK), dim3(256), 0, stream>>>(Pm, VgT, rsum, attb);

  // output projection + layernorm
  k_gemm_f32<<<dim3(8, 32), dim3(256), 0, stream>>>(attb, wob, ob, hbuf, DIMN, DIMN);
  k_ln<<<dim3(BATCHN * SEQN), dim3(256), 0, stream>>>(hbuf, lnw, lnb, hb);

  // vocab projection: 256^2 BK=32 ring-4 deep-prefetch kernel, 2000 blocks
  k_vocab<<<dim3(2000), dim3(512), 0, stream>>>(hb, woutb, outb, out);
}

// Round 7
// 604.391 us; speedup vs baseline: 1.2384x; 1.1348x over previous
//
#include <hip/hip_runtime.h>
#include <stdint.h>

#define DIMN 1024
#define SEQN 2048
#define BATCHN 2
#define NCHUNK 8
#define CHUNKSZ 256
#define VOCABN 32000
#define ROWS_PB 6016            // sum of padded nk per batch
#define PSTRIDE_B (256*ROWS_PB) // P elements per batch
#define LN_EPS 1e-5f

#define MBIG 4096
#define NBIG 32000
#define KBIG 1024
#define NTILES_K (KBIG/64)      // 16

typedef unsigned short ushort_t;
typedef __attribute__((ext_vector_type(8))) __bf16 bf16x8;
typedef __attribute__((ext_vector_type(4))) float f32x4;

__device__ const int d_nk[8]   = {256,512,768,769,769,769,769,770};
__device__ const int d_np[8]   = {256,512,768,896,896,896,896,896};
__device__ const int d_koff[8] = {0,256,768,1536,2432,3328,4224,5120};

__device__ __forceinline__ ushort_t f2bu(float f) {
  union { float f; unsigned u; } v; v.f = f;
  unsigned r = v.u + 0x7FFFu + ((v.u >> 16) & 1u);
  return (ushort_t)(r >> 16);
}
__device__ __forceinline__ float b2f(ushort_t u) {
  union { unsigned u; float f; } v; v.u = ((unsigned)u) << 16; return v.f;
}

// pos in [0,SEQ) of gathered key j for chunk i (closed form of _cache_positions)
__device__ __forceinline__ int pos_of(int i, int j) {
  if (i <= 2) return j;
  if (i <= 6) return (j == 0) ? 0 : (i - 3) * 256 + 255 + j;
  return (j == 0) ? 0 : ((j == 1) ? 1024 : 1278 + j);
}

__device__ __forceinline__ void gload16(const void* g, void* l) {
  __builtin_amdgcn_global_load_lds((__attribute__((address_space(1))) void*)g,
                                   (__attribute__((address_space(3))) void*)l,
                                   16, 0, 0);
}

// ---------------------------------------------------------------------------
// Swizzled 128x128 m97 core (conflict-free): LDS rows are 128 B, chunk slot
// XORed by (row&7).  Staging: linear LDS dest + inverse-swizzled global src
// (global_load_lds rule); reads apply the same XOR -> 0 bank conflicts
// (r1-vocab PMC-verified pattern).  K must be a multiple of 64.
// ---------------------------------------------------------------------------
__device__ __forceinline__ void mma_core_s(const ushort_t* __restrict__ A,
                                           const ushort_t* __restrict__ Bt,
                                           int K, ushort_t* lA, ushort_t* lB,
                                           f32x4 acc[4][4], int tid) {
  const int lane = tid & 63;
  const int wr = (tid >> 7) & 1;
  const int wc = (tid >> 6) & 1;
  const int frow = lane & 15;
  const int lhi = lane >> 4;
  const int xk = (frow & 7) << 4;
  const size_t ldb = (size_t)K * 2;     // row stride in bytes
  for (int kt = 0; kt < K; kt += 64) {
#pragma unroll
    for (int t = 0; t < 4; ++t) {
      int cid = t * 256 + tid;                       // 16B chunk id 0..1023
      int row = cid >> 3;                            // 0..127
      int srcoff = ((cid & 7) * 16) ^ ((row & 7) << 4);
      gload16((const char*)A  + (size_t)row * ldb + (size_t)kt * 2 + srcoff,
              (char*)lA + cid * 16);
      gload16((const char*)Bt + (size_t)row * ldb + (size_t)kt * 2 + srcoff,
              (char*)lB + cid * 16);
    }
    __syncthreads();
#pragma unroll
    for (int kk = 0; kk < 2; ++kk) {
      bf16x8 af[4], bfr[4];
#pragma unroll
      for (int m = 0; m < 4; ++m) {
        int r = wr * 64 + m * 16 + frow;
        af[m] = *(const bf16x8*)((const char*)lA +
                 ((r * 128 + kk * 64 + lhi * 16) ^ xk));
      }
#pragma unroll
      for (int n = 0; n < 4; ++n) {
        int r = wc * 64 + n * 16 + frow;
        bfr[n] = *(const bf16x8*)((const char*)lB +
                  ((r * 128 + kk * 64 + lhi * 16) ^ xk));
      }
#pragma unroll
      for (int m = 0; m < 4; ++m)
#pragma unroll
        for (int n = 0; n < 4; ++n)
          acc[m][n] = __builtin_amdgcn_mfma_f32_16x16x32_bf16(af[m], bfr[n],
                                                              acc[m][n], 0, 0, 0);
    }
    __syncthreads();
  }
}

// ===========================================================================
// Vocab projection (r1-exact best-measured): 256x256 8-wave, BK=64, double
// buffer, vmcnt(8) gate, quadrant barriers, setprio.  0 bank conflicts.
// ===========================================================================
__device__ __forceinline__ void stage_tile_big(const char* Abase, const char* Bbase,
                                               ushort_t* ldsbuf, int ktile, int tid) {
  const size_t ldb = (size_t)KBIG * 2;
#pragma unroll
  for (int s = 0; s < 4; ++s) {
    const char* base = (s < 2 ? Abase : Bbase) + (size_t)(s & 1) * 128 * ldb
                       + (size_t)ktile * 128;   // 64 bf16 cols = 128 B
    ushort_t* lh = ldsbuf + s * 8192;
#pragma unroll
    for (int r2 = 0; r2 < 2; ++r2) {
      int c = r2 * 512 + tid;                  // 16B chunk id; wave-linear LDS
      int row = c >> 3;                        // 0..127
      int off_l = (c * 16) ^ ((row & 7) << 4); // inverse swizzle on source
      gload16(base + (size_t)row * ldb + (off_l & 127), (char*)lh + c * 16);
    }
  }
}

__global__ __launch_bounds__(512, 2) void k_vocab(
    const ushort_t* __restrict__ A, const ushort_t* __restrict__ Bt,
    const float* __restrict__ bias, float* __restrict__ C) {
  __shared__ ushort_t lds[2][4][8192];   // per buf {A-h0, A-h1, B-h0, B-h1}
  const int tid = threadIdx.x;
  const int lane = tid & 63, w = tid >> 6, wm = w >> 2, wn = w & 3;
  const int frow = lane & 15, lhi = lane >> 4;
  const int xk = (frow & 7) << 4;        // read-side swizzle XOR

  int l = blockIdx.x;
  int swz = (l & 7) * ((int)gridDim.x >> 3) + (l >> 3);
  const int mt = swz & 15;               // MBIG/256 = 16
  const int nt = swz >> 4;               // 0..124
  const char* Abase = (const char*)(A + (size_t)mt * 256 * KBIG);
  const char* Bbase = (const char*)(Bt + (size_t)nt * 256 * KBIG);

  f32x4 acc[8][4] = {};

  stage_tile_big(Abase, Bbase, &lds[0][0][0], 0, tid);

  for (int kt = 0; kt < NTILES_K; ++kt) {
    const int cur = kt & 1;
    __builtin_amdgcn_sched_barrier(0);
    if (kt + 1 < NTILES_K) {
      stage_tile_big(Abase, Bbase, &lds[cur ^ 1][0][0], kt + 1, tid);
      asm volatile("s_waitcnt vmcnt(8)");    // oldest 8 = tile kt landed
    } else {
      asm volatile("s_waitcnt vmcnt(0)");
    }
    __builtin_amdgcn_s_barrier();
    __builtin_amdgcn_sched_barrier(0);

    const char* lA = (const char*)&lds[cur][wm][0];
    const char* lB = (const char*)&lds[cur][2 + (wn >> 1)][0];

    bf16x8 bF[4][2];
#pragma unroll
    for (int fc = 0; fc < 4; ++fc) {
      int c = (wn & 1) * 64 + fc * 16 + frow;
#pragma unroll
      for (int kk = 0; kk < 2; ++kk)
        bF[fc][kk] = *(const bf16x8*)(lB + ((c * 128 + kk * 64 + lhi * 16) ^ xk));
    }
#pragma unroll
    for (int q = 0; q < 4; ++q) {
      bf16x8 aF[2][2];
#pragma unroll
      for (int i = 0; i < 2; ++i) {
        int r = (2 * q + i) * 16 + frow;
#pragma unroll
        for (int kk = 0; kk < 2; ++kk)
          aF[i][kk] = *(const bf16x8*)(lA + ((r * 128 + kk * 64 + lhi * 16) ^ xk));
      }
      if (q) __builtin_amdgcn_s_barrier();
      __builtin_amdgcn_s_setprio(1);
#pragma unroll
      for (int i = 0; i < 2; ++i)
#pragma unroll
        for (int fc = 0; fc < 4; ++fc)
#pragma unroll
          for (int kk = 0; kk < 2; ++kk)
            acc[2 * q + i][fc] = __builtin_amdgcn_mfma_f32_16x16x32_bf16(
                aF[i][kk], bF[fc][kk], acc[2 * q + i][fc], 0, 0, 0);
      __builtin_amdgcn_s_setprio(0);
    }
    __builtin_amdgcn_s_barrier();
  }

  const int rbase = mt * 256 + wm * 128 + lhi * 4;
  const int cbase = nt * 256 + wn * 64 + frow;
#pragma unroll
  for (int fc = 0; fc < 4; ++fc) {
    float bv = bias[cbase + fc * 16];
#pragma unroll
    for (int fr = 0; fr < 8; ++fr)
#pragma unroll
      for (int j = 0; j < 4; ++j)
        C[(size_t)(rbase + fr * 16 + j) * NBIG + cbase + fc * 16] =
            acc[fr][fc][j] + bv;
  }
}

// ---------------------------------------------------------------------------
__global__ __launch_bounds__(256) void k_cvt(const float* __restrict__ src,
                                             ushort_t* __restrict__ dst, int n) {
  int idx = blockIdx.x * 256 + threadIdx.x;
  int stride = gridDim.x * 256;
  int n4 = n >> 2;
  for (int i = idx; i < n4; i += stride) {
    float4 v = ((const float4*)src)[i];
    ((ushort4*)dst)[i] = make_ushort4(f2bu(v.x), f2bu(v.y), f2bu(v.z), f2bu(v.w));
  }
}

// ctx[b,t] = sum_{o=0..3, t-o>=0} emb[x[b,t-o]]  -> bf16
__global__ __launch_bounds__(256) void k_embed(const int* __restrict__ x,
                                               const float* __restrict__ emb,
                                               ushort_t* __restrict__ ctxb) {
  const int t = blockIdx.x, b = blockIdx.y, tid = threadIdx.x;
  float4 s = make_float4(0.f, 0.f, 0.f, 0.f);
#pragma unroll
  for (int o = 0; o < 4; ++o) {
    if (t - o < 0) break;
    int tok = x[b * SEQN + t - o];
    float4 v = ((const float4*)(emb + (size_t)tok * DIMN))[tid];
    s.x += v.x; s.y += v.y; s.z += v.z; s.w += v.w;
  }
  ((ushort4*)(ctxb + ((size_t)(b * SEQN + t)) * DIMN))[tid] =
      make_ushort4(f2bu(s.x), f2bu(s.y), f2bu(s.z), f2bu(s.w));
}

// fused QKV: A(4096x1024) x wqkv^T(3072x1024); epilogue routes cols to Q/K/V.
__global__ __launch_bounds__(256) void k_qkv(const ushort_t* __restrict__ A,
    const ushort_t* __restrict__ Bt, const float* __restrict__ qb2,
    const float* __restrict__ kb2, const float* __restrict__ vb2,
    ushort_t* __restrict__ Qb, ushort_t* __restrict__ Kb,
    ushort_t* __restrict__ Vb) {
  __shared__ __align__(16) ushort_t lA[128*64];
  __shared__ __align__(16) ushort_t lB[128*64];
  f32x4 acc[4][4] = {};
  const int tid = threadIdx.x;
  mma_core_s(A + (size_t)blockIdx.y * 128 * KBIG,
             Bt + (size_t)blockIdx.x * 128 * KBIG, KBIG, lA, lB, acc, tid);
  const int which = blockIdx.x >> 3;           // 0:Q 1:K 2:V (wave-uniform)
  const int col0  = (blockIdx.x & 7) * 128;
  ushort_t* Out = (which == 0) ? Qb : (which == 1) ? Kb : Vb;
  const float* Bv = (which == 0) ? qb2 : (which == 1) ? kb2 : vb2;
  const int lane = tid & 63, wr = (tid >> 7) & 1, wc = (tid >> 6) & 1;
  const int rbase = blockIdx.y * 128 + wr * 64 + (lane >> 4) * 4;
  const int cbase = col0 + wc * 64 + (lane & 15);
#pragma unroll
  for (int m = 0; m < 4; ++m)
#pragma unroll
    for (int n = 0; n < 4; ++n) {
      int c = cbase + n * 16;
      float bv = Bv[c];
#pragma unroll
      for (int j = 0; j < 4; ++j)
        Out[(size_t)(rbase + m * 16 + j) * DIMN + c] = f2bu(acc[m][n][j] + bv);
    }
}

__global__ __launch_bounds__(256) void k_gemm_f32(const ushort_t* __restrict__ A,
    const ushort_t* __restrict__ Bt, const float* __restrict__ bias,
    float* __restrict__ C, int N, int K) {
  __shared__ __align__(16) ushort_t lA[128*64];
  __shared__ __align__(16) ushort_t lB[128*64];
  f32x4 acc[4][4] = {};
  const int tid = threadIdx.x;
  mma_core_s(A + (size_t)blockIdx.y * 128 * K, Bt + (size_t)blockIdx.x * 128 * K,
             K, lA, lB, acc, tid);
  const int lane = tid & 63, wr = (tid >> 7) & 1, wc = (tid >> 6) & 1;
  const int rbase = blockIdx.y * 128 + wr * 64 + (lane >> 4) * 4;
  const int cbase = blockIdx.x * 128 + wc * 64 + (lane & 15);
#pragma unroll
  for (int m = 0; m < 4; ++m)
#pragma unroll
    for (int n = 0; n < 4; ++n) {
      int c = cbase + n * 16;
      float bv = bias[c];
#pragma unroll
      for (int j = 0; j < 4; ++j)
        C[(size_t)(rbase + m * 16 + j) * N + c] = acc[m][n][j] + bv;
    }
}

// gather K rows into padded contiguous [b][ROWS_PB][DIM] (zeros in pad)
__global__ __launch_bounds__(256) void k_gatherK(const ushort_t* __restrict__ Kb,
                                                 ushort_t* __restrict__ Kg) {
  const int r = blockIdx.x, b = blockIdx.y, tid = threadIdx.x;
  int i = 7;
#pragma unroll
  for (int q = 0; q < 7; ++q) if (r < d_koff[q + 1]) { i = q; break; }
  const int j = r - d_koff[i];
  ushort4* dst = (ushort4*)(Kg + ((size_t)b * ROWS_PB + r) * DIMN);
  if (j < d_nk[i]) {
    int pos = pos_of(i, j);
    dst[tid] = ((const ushort4*)(Kb + ((size_t)b * SEQN + pos) * DIMN))[tid];
  } else {
    dst[tid] = make_ushort4(0, 0, 0, 0);
  }
}

// transpose-gather V -> VgT[b][chunk]: [DIM][np] (zeros in pad)
__global__ __launch_bounds__(256) void k_transV(const ushort_t* __restrict__ Vb,
                                                ushort_t* __restrict__ VgT) {
  __shared__ ushort_t tile[64][66];
  const int z = blockIdx.z, b = z >> 3, i = z & 7;
  const int np = d_np[i], nk = d_nk[i], ko = d_koff[i];
  const int jb = blockIdx.x * 64;
  if (jb >= np) return;
  const int db = blockIdx.y * 64;
  const int tid = threadIdx.x, tx = tid & 63, ty = tid >> 6;
#pragma unroll
  for (int rep = 0; rep < 16; ++rep) {
    int jl = rep * 4 + ty;
    int j = jb + jl;
    ushort_t v = 0;
    if (j < nk) v = Vb[((size_t)b * SEQN + pos_of(i, j)) * DIMN + db + tx];
    tile[jl][tx] = v;
  }
  __syncthreads();
  const size_t base = ((size_t)b * ROWS_PB + ko) * DIMN;
#pragma unroll
  for (int rep = 0; rep < 16; ++rep) {
    int dl = rep * 4 + ty;
    VgT[base + (size_t)(db + dl) * np + jb + tx] = tile[tx][dl];
  }
}

// scores: P = exp(scale * Q Kg^T) with causal/pad mask -> bf16
__global__ __launch_bounds__(256) void k_scores(const ushort_t* __restrict__ Qb,
    const ushort_t* __restrict__ Kg, ushort_t* __restrict__ P) {
  const int z = blockIdx.z, b = z >> 3, i = z & 7;
  const int np = d_np[i], nk = d_nk[i], ko = d_koff[i];
  if ((int)blockIdx.x * 128 >= np) return;
  __shared__ __align__(16) ushort_t lA[128*64];
  __shared__ __align__(16) ushort_t lB[128*64];
  f32x4 acc[4][4] = {};
  const int tid = threadIdx.x;
  const ushort_t* A  = Qb + ((size_t)(b * SEQN + i * CHUNKSZ) + blockIdx.y * 128) * DIMN;
  const ushort_t* Bt = Kg + ((size_t)b * ROWS_PB + ko + blockIdx.x * 128) * DIMN;
  mma_core_s(A, Bt, DIMN, lA, lB, acc, tid);
  const int lane = tid & 63, wr = (tid >> 7) & 1, wc = (tid >> 6) & 1;
  const int rb = blockIdx.y * 128 + wr * 64 + (lane >> 4) * 4;
  const int cb = blockIdx.x * 128 + wc * 64 + (lane & 15);
  ushort_t* Pc = P + (size_t)b * PSTRIDE_B + (size_t)ko * 256;
  const float scale = 0.03125f;  // 1/sqrt(1024)
  const int diag0 = nk - CHUNKSZ;
#pragma unroll
  for (int m = 0; m < 4; ++m)
#pragma unroll
    for (int n = 0; n < 4; ++n) {
      int c = cb + n * 16;
#pragma unroll
      for (int j = 0; j < 4; ++j) {
        int r = rb + m * 16 + j;
        float w = 0.0f;
        if (c < nk && (c - diag0) <= r) w = expf(acc[m][n][j] * scale);
        Pc[(size_t)r * np + c] = f2bu(w);
      }
    }
}

// deterministic row sums of P (bf16 values, f32 accumulate)
__global__ __launch_bounds__(256) void k_rowsum(const ushort_t* __restrict__ P,
                                                float* __restrict__ rowsum) {
  const int z = blockIdx.y, b = z >> 3, i = z & 7, r = blockIdx.x;
  const int np = d_np[i], ko = d_koff[i];
  const ushort_t* row = P + (size_t)b * PSTRIDE_B + (size_t)ko * 256 + (size_t)r * np;
  const int tid = threadIdx.x;
  float s = 0.f;
  for (int c = tid; c < np; c += 256) s += b2f(row[c]);
#pragma unroll
  for (int o = 1; o < 64; o <<= 1) s += __shfl_xor(s, o);
  __shared__ float ss[4];
  if ((tid & 63) == 0) ss[tid >> 6] = s;
  __syncthreads();
  if (tid == 0) rowsum[z * 256 + r] = ss[0] + ss[1] + ss[2] + ss[3];
}

// attended = (P @ Vg) / rowsum -> bf16
__global__ __launch_bounds__(256) void k_pv(const ushort_t* __restrict__ P,
    const ushort_t* __restrict__ VgT, const float* __restrict__ rowsum,
    ushort_t* __restrict__ attb) {
  const int z = blockIdx.z, b = z >> 3, i = z & 7;
  const int np = d_np[i], ko = d_koff[i];
  __shared__ __align__(16) ushort_t lA[128*64];
  __shared__ __align__(16) ushort_t lB[128*64];
  f32x4 acc[4][4] = {};
  const int tid = threadIdx.x;
  const ushort_t* A  = P + (size_t)b * PSTRIDE_B + (size_t)ko * 256 +
                       (size_t)blockIdx.y * 128 * np;
  const ushort_t* Bt = VgT + ((size_t)b * ROWS_PB + ko) * DIMN +
                       (size_t)blockIdx.x * 128 * np;
  mma_core_s(A, Bt, np, lA, lB, acc, tid);
  const int lane = tid & 63, wr = (tid >> 7) & 1, wc = (tid >> 6) & 1;
  const int rb = blockIdx.y * 128 + wr * 64 + (lane >> 4) * 4;
  const int cb = blockIdx.x * 128 + wc * 64 + (lane & 15);
  const float* rs = rowsum + z * 256;
  ushort_t* outp = attb + (size_t)(b * SEQN + i * CHUNKSZ) * DIMN;
#pragma unroll
  for (int m = 0; m < 4; ++m)
#pragma unroll
    for (int j = 0; j < 4; ++j) {
      int r = rb + m * 16 + j;
      float inv = 1.0f / rs[r];
#pragma unroll
      for (int n = 0; n < 4; ++n)
        outp[(size_t)r * DIMN + cb + n * 16] = f2bu(acc[m][n][j] * inv);
    }
}

__global__ __launch_bounds__(256) void k_ln(const float* __restrict__ h,
    const float* __restrict__ lnw, const float* __restrict__ lnb,
    ushort_t* __restrict__ hb) {
  const int row = blockIdx.x, tid = threadIdx.x;
  float4 v = ((const float4*)(h + (size_t)row * DIMN))[tid];
  float s  = v.x + v.y + v.z + v.w;
  float sq = v.x * v.x + v.y * v.y + v.z * v.z + v.w * v.w;
#pragma unroll
  for (int o = 1; o < 64; o <<= 1) { s += __shfl_xor(s, o); sq += __shfl_xor(sq, o); }
  __shared__ float ss[4], ssq[4];
  if ((tid & 63) == 0) { ss[tid >> 6] = s; ssq[tid >> 6] = sq; }
  __syncthreads();
  s  = ss[0] + ss[1] + ss[2] + ss[3];
  sq = ssq[0] + ssq[1] + ssq[2] + ssq[3];
  const float mu  = s * (1.0f / DIMN);
  const float var = sq * (1.0f / DIMN) - mu * mu;
  const float inv = rsqrtf(var + LN_EPS);
  float4 w4 = ((const float4*)lnw)[tid];
  float4 b4 = ((const float4*)lnb)[tid];
  ushort4 o4 = make_ushort4(f2bu((v.x - mu) * inv * w4.x + b4.x),
                            f2bu((v.y - mu) * inv * w4.y + b4.y),
                            f2bu((v.z - mu) * inv * w4.z + b4.z),
                            f2bu((v.w - mu) * inv * w4.w + b4.w));
  ((ushort4*)(hb + (size_t)row * DIMN))[tid] = o4;
}

// ---------------------------------------------------------------------------
extern "C" void kernel_launch(void* const* d_in, const int* in_sizes, int n_in,
                              void* d_out, int out_size, void* d_ws, size_t ws_size,
                              hipStream_t stream) {
  const int*   x    = (const int*)  d_in[0];
  const float* emb  = (const float*)d_in[1];
  const float* qw   = (const float*)d_in[2];
  const float* qb   = (const float*)d_in[3];
  const float* kw   = (const float*)d_in[4];
  const float* kb   = (const float*)d_in[5];
  const float* vw   = (const float*)d_in[6];
  const float* vb   = (const float*)d_in[7];
  const float* ow   = (const float*)d_in[8];
  const float* ob   = (const float*)d_in[9];
  const float* lnw  = (const float*)d_in[10];
  const float* lnb  = (const float*)d_in[11];
  const float* outw = (const float*)d_in[12];
  const float* outb = (const float*)d_in[13];
  float* out = (float*)d_out;
  (void)in_sizes; (void)n_in; (void)out_size; (void)ws_size;

  char* ws = (char*)d_ws;
  size_t off = 0;
  auto alloc = [&](size_t bytes) {
    size_t r = off; off += (bytes + 255) & ~(size_t)255; return r;
  };
  ushort_t* wqkvb = (ushort_t*)(ws + alloc((size_t)3 * DIMN * DIMN * 2));
  ushort_t* wob   = (ushort_t*)(ws + alloc((size_t)DIMN * DIMN * 2));
  ushort_t* woutb = (ushort_t*)(ws + alloc((size_t)VOCABN * DIMN * 2));
  ushort_t* ctxb  = (ushort_t*)(ws + alloc((size_t)BATCHN * SEQN * DIMN * 2));
  ushort_t* Qb    = (ushort_t*)(ws + alloc((size_t)BATCHN * SEQN * DIMN * 2));
  ushort_t* Kb    = (ushort_t*)(ws + alloc((size_t)BATCHN * SEQN * DIMN * 2));
  ushort_t* Vb    = (ushort_t*)(ws + alloc((size_t)BATCHN * SEQN * DIMN * 2));
  ushort_t* Kg    = (ushort_t*)(ws + alloc((size_t)BATCHN * ROWS_PB * DIMN * 2));
  ushort_t* VgT   = (ushort_t*)(ws + alloc((size_t)BATCHN * ROWS_PB * DIMN * 2));
  ushort_t* Pm    = (ushort_t*)(ws + alloc((size_t)BATCHN * PSTRIDE_B * 2));
  float*    rsum  = (float*)   (ws + alloc((size_t)BATCHN * NCHUNK * 256 * 4));
  ushort_t* attb  = (ushort_t*)(ws + alloc((size_t)BATCHN * SEQN * DIMN * 2));
  float*    hbuf  = (float*)   (ws + alloc((size_t)BATCHN * SEQN * DIMN * 4));
  ushort_t* hb    = (ushort_t*)(ws + alloc((size_t)BATCHN * SEQN * DIMN * 2));

  // weight conversions f32 -> bf16 (QKV packed into one 3072x1024 buffer)
  k_cvt<<<dim3(1024), dim3(256), 0, stream>>>(qw, wqkvb,                 DIMN * DIMN);
  k_cvt<<<dim3(1024), dim3(256), 0, stream>>>(kw, wqkvb + DIMN * DIMN,   DIMN * DIMN);
  k_cvt<<<dim3(1024), dim3(256), 0, stream>>>(vw, wqkvb + 2 * DIMN * DIMN, DIMN * DIMN);
  k_cvt<<<dim3(1024), dim3(256), 0, stream>>>(ow,   wob,   DIMN * DIMN);
  k_cvt<<<dim3(2048), dim3(256), 0, stream>>>(outw, woutb, VOCABN * DIMN);

  // embedding + 4-tap context sum
  k_embed<<<dim3(SEQN, BATCHN), dim3(256), 0, stream>>>(x, emb, ctxb);

  // fused QKV projection (24 n-tiles x 32 m-tiles = 768 blocks)
  k_qkv<<<dim3(24, 32), dim3(256), 0, stream>>>(ctxb, wqkvb, qb, kb, vb,
                                                Qb, Kb, Vb);

  // sparse KV gather
  k_gatherK<<<dim3(ROWS_PB, BATCHN), dim3(256), 0, stream>>>(Kb, Kg);
  k_transV<<<dim3(14, 16, BATCHN * NCHUNK), dim3(256), 0, stream>>>(Vb, VgT);

  // attention
  k_scores<<<dim3(7, 2, BATCHN * NCHUNK), dim3(256), 0, stream>>>(Qb, Kg, Pm);
  k_rowsum<<<dim3(256, BATCHN * NCHUNK), dim3(256), 0, stream>>>(Pm, rsum);
  k_pv<<<dim3(8, 2, BATCHN * NCHUNK), dim3(256), 0, stream>>>(Pm, VgT, rsum, attb);

  // output projection + layernorm
  k_gemm_f32<<<dim3(8, 32), dim3(256), 0, stream>>>(attb, wob, ob, hbuf, DIMN, DIMN);
  k_ln<<<dim3(BATCHN * SEQN), dim3(256), 0, stream>>>(hbuf, lnw, lnb, hb);

  // vocab projection: r1-exact 256^2 kernel, 2000 blocks
  k_vocab<<<dim3(2000), dim3(512), 0, stream>>>(hb, woutb, outb, out);
}